// Round 1
// baseline (116.368 us; speedup 1.0000x reference)
//
#include <hip/hip_runtime.h>

// PatchQuantumGenerator: 5-qubit statevector sim.
// out[b, g*16+k] = probs[k] / max_k(probs[:16]) after circuit:
//   RY(x[b,q]) on each qubit q, then 4 layers of
//   (Rot(w[g,l,q,:]) on each q; CNOT(q, (q+l+1)%5) for each q)
// Wire w <-> bit mask (16>>w) in the flattened 32-amplitude index.

#define NGEN 4
#define NLAY 4
#define NQ   5

__global__ __launch_bounds__(256) void pqg_kernel(
    const float* __restrict__ x,      // [B,5]
    const float* __restrict__ w,      // [4,4,5,3]
    float* __restrict__ out)          // [B,64]
{
    // Per-g stride 164 (not 160): 4 g-slots map to distinct LDS bank quads,
    // so ds_read_b128 with 4 distinct g addresses per wave is conflict-free.
    __shared__ float sm[NGEN * 164];

    const int tid = threadIdx.x;

    // Threads 0..79 each build one Rot 2x2 complex matrix into LDS.
    if (tid < NGEN * NLAY * NQ) {
        const int g = tid / (NLAY * NQ);
        const int rem = tid % (NLAY * NQ);           // l*5+q
        const float* wp = w + (g * (NLAY * NQ) + rem) * 3;
        const float phi = wp[0], theta = wp[1], omega = wp[2];
        const float a = 0.5f * (phi + omega);
        const float b = 0.5f * (phi - omega);
        const float h = 0.5f * theta;
        const float sa = __sinf(a), ca = __cosf(a);
        const float sb = __sinf(b), cb = __cosf(b);
        const float st = __sinf(h), ct = __cosf(h);
        float* m = &sm[g * 164 + rem * 8];
        // Rot = RZ(omega) RY(theta) RZ(phi):
        // U00 = e^{-ia} c ; U01 = -conj(e^{-ib}) s ; U10 = e^{-ib} s ; U11 = conj(e^{-ia}) c
        m[0] =  ca * ct;  m[1] = -sa * ct;
        m[2] = -cb * st;  m[3] = -sb * st;
        m[4] =  cb * st;  m[5] = -sb * st;
        m[6] =  ca * ct;  m[7] =  sa * ct;
    }
    __syncthreads();

    const int gt = blockIdx.x * 256 + tid;
    const int b = gt >> 2;        // batch index
    const int g = gt & 3;         // generator index

    // Statevector in registers (fully unrolled below keeps indices constant).
    float sr[32], si[32];
#pragma unroll
    for (int i = 0; i < 32; ++i) { sr[i] = 0.0f; si[i] = 0.0f; }
    sr[0] = 1.0f;

    // Initial RY(noise) layer.
#pragma unroll
    for (int q = 0; q < NQ; ++q) {
        const float t = 0.5f * x[b * NQ + q];
        const float s = __sinf(t), c = __cosf(t);
        const int sb = 16 >> q;
#pragma unroll
        for (int i = 0; i < 32; ++i) {
            if (!(i & sb)) {
                const int j = i | sb;
                const float ar = sr[i], ai = si[i], br = sr[j], bi = si[j];
                sr[i] = c * ar - s * br;  si[i] = c * ai - s * bi;
                sr[j] = s * ar + c * br;  si[j] = s * ai + c * bi;
            }
        }
    }

    const float* smg = &sm[g * 164];

    // 4 StronglyEntangling layers.
#pragma unroll
    for (int l = 0; l < NLAY; ++l) {
        // Rot gates.
#pragma unroll
        for (int q = 0; q < NQ; ++q) {
            const float* m = &smg[(l * NQ + q) * 8];
            const float u00r = m[0], u00i = m[1], u01r = m[2], u01i = m[3];
            const float u10r = m[4], u10i = m[5], u11r = m[6], u11i = m[7];
            const int sb = 16 >> q;
#pragma unroll
            for (int i = 0; i < 32; ++i) {
                if (!(i & sb)) {
                    const int j = i | sb;
                    const float ar = sr[i], ai = si[i], br = sr[j], bi = si[j];
                    sr[i] = u00r * ar - u00i * ai + u01r * br - u01i * bi;
                    si[i] = u00r * ai + u00i * ar + u01r * bi + u01i * br;
                    sr[j] = u10r * ar - u10i * ai + u11r * br - u11i * bi;
                    si[j] = u10r * ai + u10i * ar + u11r * bi + u11i * br;
                }
            }
        }
        // CNOT ring: control q, target (q+l+1)%5. Pure register permutation.
        const int r = l + 1;
#pragma unroll
        for (int q = 0; q < NQ; ++q) {
            const int cb = 16 >> q;
            const int tb = 16 >> ((q + r) % NQ);
#pragma unroll
            for (int i = 0; i < 32; ++i) {
                if ((i & cb) && !(i & tb)) {
                    const int j = i | tb;
                    float tr = sr[i]; sr[i] = sr[j]; sr[j] = tr;
                    float ti = si[i]; si[i] = si[j]; si[j] = ti;
                }
            }
        }
    }

    // probs[:16] / max  (the /sum cancels in the max-normalization).
    float p[16];
    float mx = 0.0f;
#pragma unroll
    for (int k = 0; k < 16; ++k) {
        p[k] = sr[k] * sr[k] + si[k] * si[k];
        mx = fmaxf(mx, p[k]);
    }
    const float inv = 1.0f / mx;

    float4* o = (float4*)out + gt * 4;   // out + gt*16 floats, contiguous per thread
#pragma unroll
    for (int k = 0; k < 4; ++k) {
        o[k] = make_float4(p[4 * k + 0] * inv, p[4 * k + 1] * inv,
                           p[4 * k + 2] * inv, p[4 * k + 3] * inv);
    }
}

extern "C" void kernel_launch(void* const* d_in, const int* in_sizes, int n_in,
                              void* d_out, int out_size, void* d_ws, size_t ws_size,
                              hipStream_t stream) {
    const float* x = (const float*)d_in[0];   // [65536, 5]
    const float* w = (const float*)d_in[1];   // [4, 4, 5, 3]
    float* out = (float*)d_out;               // [65536, 64]
    const int B = in_sizes[0] / NQ;           // 65536
    const int total = B * NGEN;               // 262144 threads, one per (b,g)
    pqg_kernel<<<total / 256, 256, 0, stream>>>(x, w, out);
}

// Round 2
// 86.246 us; speedup vs baseline: 1.3493x; 1.3493x over previous
//
#include <hip/hip_runtime.h>

// PatchQuantumGenerator, round 2: circuit folded into a fixed linear map.
//
// State after the initial RY layer is REAL and rank-1: v(b)[i] = prod_q
// (bit_q(i) ? sin : cos)(x[b,q]/2). The 4 entangling layers form a fixed
// complex unitary U_g per generator. out amps = M_g (rows 0..15 of U_g) * v.
// => precompute M_g once (kernel A), then a f16 MFMA GEMM (kernel B).

#define NGEN 4
#define NLAY 4
#define NQ   5

typedef _Float16 half8 __attribute__((ext_vector_type(8)));
typedef float    f32x4 __attribute__((ext_vector_type(4)));

// ---------------------------------------------------------------------------
// Kernel A: per (g, col) simulate basis state |col> through the 4 layers,
// store rows 0..15 of the resulting column in f16 MFMA A-fragment layout:
//   element (m, k): lane L = (k>>3)*16 + m, reg j = k&7
//   ws layout: plane p (0=re,1=im): ws[((g*2+p)*64 + L)*8 + j]
// ---------------------------------------------------------------------------
__global__ void pqg_precompute(const float* __restrict__ w, _Float16* __restrict__ wsA) {
    __shared__ float sm[NLAY * NQ * 8];
    const int g = blockIdx.x;
    const int tid = threadIdx.x;   // 0..31

    if (tid < NLAY * NQ) {
        const float* wp = w + (g * (NLAY * NQ) + tid) * 3;
        const float phi = wp[0], theta = wp[1], omega = wp[2];
        const float a = 0.5f * (phi + omega);
        const float bb = 0.5f * (phi - omega);
        const float h = 0.5f * theta;
        const float sa = __sinf(a), ca = __cosf(a);
        const float sb = __sinf(bb), cb = __cosf(bb);
        const float st = __sinf(h), ct = __cosf(h);
        float* m = &sm[tid * 8];
        // Rot = RZ(omega) RY(theta) RZ(phi)  (verified in round 1)
        m[0] =  ca * ct;  m[1] = -sa * ct;
        m[2] = -cb * st;  m[3] = -sb * st;
        m[4] =  cb * st;  m[5] = -sb * st;
        m[6] =  ca * ct;  m[7] =  sa * ct;
    }
    __syncthreads();

    const int col = tid;           // basis state index
    float sr[32], si[32];
#pragma unroll
    for (int i = 0; i < 32; ++i) { sr[i] = (i == col) ? 1.0f : 0.0f; si[i] = 0.0f; }

#pragma unroll
    for (int l = 0; l < NLAY; ++l) {
#pragma unroll
        for (int q = 0; q < NQ; ++q) {
            const float* m = &sm[(l * NQ + q) * 8];
            const float u00r = m[0], u00i = m[1], u01r = m[2], u01i = m[3];
            const float u10r = m[4], u10i = m[5], u11r = m[6], u11i = m[7];
            const int sb2 = 16 >> q;
#pragma unroll
            for (int i = 0; i < 32; ++i) {
                if (!(i & sb2)) {
                    const int j = i | sb2;
                    const float ar = sr[i], ai = si[i], br = sr[j], bi = si[j];
                    sr[i] = u00r * ar - u00i * ai + u01r * br - u01i * bi;
                    si[i] = u00r * ai + u00i * ar + u01r * bi + u01i * br;
                    sr[j] = u10r * ar - u10i * ai + u11r * br - u11i * bi;
                    si[j] = u10r * ai + u10i * ar + u11r * bi + u11i * br;
                }
            }
        }
        const int r = l + 1;
#pragma unroll
        for (int q = 0; q < NQ; ++q) {
            const int cbm = 16 >> q;
            const int tbm = 16 >> ((q + r) % NQ);
#pragma unroll
            for (int i = 0; i < 32; ++i) {
                if ((i & cbm) && !(i & tbm)) {
                    const int j = i | tbm;
                    float tr = sr[i]; sr[i] = sr[j]; sr[j] = tr;
                    float ti = si[i]; si[i] = si[j]; si[j] = ti;
                }
            }
        }
    }

    // Emit A-fragment: this thread owns column k=col; rows m=0..15.
    const int quad = col >> 3;
    const int j = col & 7;
#pragma unroll
    for (int m = 0; m < 16; ++m) {
        const int L = quad * 16 + m;
        wsA[((g * 2 + 0) * 64 + L) * 8 + j] = (_Float16)sr[m];
        wsA[((g * 2 + 1) * 64 + L) * 8 + j] = (_Float16)si[m];
    }
}

// ---------------------------------------------------------------------------
// Kernel B: wave w handles g=w; each MFMA tile = 16 batches.
// Lane (quad, n): builds B-frag entries B[k=quad*8+j][n] = v(b=n)[k].
// k bit->qubit map (weight 16>>q): bit4->q0, bit3->q1, bit2->q2, bit1->q3,
// bit0->q4. So quad&2 selects sin/cos of q0, quad&1 of q1, j bits of q2..q4.
// ---------------------------------------------------------------------------
#define TPB 4   // 16-batch tiles per block

__global__ __launch_bounds__(256) void pqg_main(
    const float* __restrict__ x,
    const _Float16* __restrict__ wsA,
    float* __restrict__ out)
{
    const int lane = threadIdx.x & 63;
    const int g = threadIdx.x >> 6;
    const int quad = lane >> 4;
    const int n = lane & 15;

    // A fragments: loaded once, reused over all tiles.
    const half8 Ar = *(const half8*)(wsA + ((g * 2 + 0) * 64 + lane) * 8);
    const half8 Ai = *(const half8*)(wsA + ((g * 2 + 1) * 64 + lane) * 8);

    const int b_block = blockIdx.x * (16 * TPB);

#pragma unroll
    for (int t = 0; t < TPB; ++t) {
        const int b = b_block + t * 16 + n;
        const float* xb = x + b * NQ;

        float c[5], s[5];
#pragma unroll
        for (int q = 0; q < 5; ++q) {
            const float tt = 0.5f * xb[q];
            s[q] = __sinf(tt);
            c[q] = __cosf(tt);
        }

        const float f01 = ((quad & 2) ? s[0] : c[0]) * ((quad & 1) ? s[1] : c[1]);
        const float a0 = f01 * c[2], a1 = f01 * s[2];
        const float b00 = a0 * c[3], b01 = a0 * s[3];
        const float b10 = a1 * c[3], b11 = a1 * s[3];

        half8 Bf;
        Bf[0] = (_Float16)(b00 * c[4]);  Bf[1] = (_Float16)(b00 * s[4]);
        Bf[2] = (_Float16)(b01 * c[4]);  Bf[3] = (_Float16)(b01 * s[4]);
        Bf[4] = (_Float16)(b10 * c[4]);  Bf[5] = (_Float16)(b10 * s[4]);
        Bf[6] = (_Float16)(b11 * c[4]);  Bf[7] = (_Float16)(b11 * s[4]);

        f32x4 accR = {0.f, 0.f, 0.f, 0.f};
        f32x4 accI = {0.f, 0.f, 0.f, 0.f};
        accR = __builtin_amdgcn_mfma_f32_16x16x32_f16(Ar, Bf, accR, 0, 0, 0);
        accI = __builtin_amdgcn_mfma_f32_16x16x32_f16(Ai, Bf, accI, 0, 0, 0);

        // C/D layout: col = lane&15 (batch n), row = quad*4 + reg (output k).
        float p0 = accR[0] * accR[0] + accI[0] * accI[0];
        float p1 = accR[1] * accR[1] + accI[1] * accI[1];
        float p2 = accR[2] * accR[2] + accI[2] * accI[2];
        float p3 = accR[3] * accR[3] + accI[3] * accI[3];

        float mx = fmaxf(fmaxf(p0, p1), fmaxf(p2, p3));
        mx = fmaxf(mx, __shfl_xor(mx, 16));
        mx = fmaxf(mx, __shfl_xor(mx, 32));
        const float inv = 1.0f / mx;

        float4 o = make_float4(p0 * inv, p1 * inv, p2 * inv, p3 * inv);
        *(float4*)(out + (size_t)b * 64 + g * 16 + quad * 4) = o;
    }
}

extern "C" void kernel_launch(void* const* d_in, const int* in_sizes, int n_in,
                              void* d_out, int out_size, void* d_ws, size_t ws_size,
                              hipStream_t stream) {
    const float* x = (const float*)d_in[0];   // [B, 5]
    const float* w = (const float*)d_in[1];   // [4, 4, 5, 3]
    float* out = (float*)d_out;               // [B, 64]
    _Float16* wsA = (_Float16*)d_ws;          // 4 g * 2 planes * 64 lanes * 8 f16 = 8 KB

    const int B = in_sizes[0] / NQ;           // 65536

    pqg_precompute<<<NGEN, 32, 0, stream>>>(w, wsA);
    pqg_main<<<B / (16 * TPB), 256, 0, stream>>>(x, wsA, out);
}

// Round 3
// 72.354 us; speedup vs baseline: 1.6083x; 1.1920x over previous
//
#include <hip/hip_runtime.h>

// PatchQuantumGenerator, round 3.
// Same algorithm as round 2 (circuit folded to M_g[16x32] per generator,
// f16 MFMA GEMM against rank-1 real v(b)), but:
//  - precompute rewritten as a cooperative SMALL-CODE kernel (rolled gate
//    loop, 32x32 state in LDS, CNOT layer as one index permutation) to kill
//    the cold-I-cache serial fetch of the old 30KB unrolled body.
//  - main grid 1024->2048 blocks (TPB 4->2) for 8 blocks/CU residency.

#define NGEN 4
#define NLAY 4
#define NQ   5

typedef _Float16 half8 __attribute__((ext_vector_type(8)));
typedef float    f32x4 __attribute__((ext_vector_type(4)));

// ---------------------------------------------------------------------------
// Kernel A: one block per g, 256 threads. State S[amp][col] (32x32 complex)
// in LDS = full unitary of the 4 entangling layers. Rolled loops keep the
// code ~2KB. Emits rows 0..15 as f16 MFMA A-fragments into wsA:
//   element (m,k): lane L=(k>>3)*16+m, reg j=k&7;
//   plane p (0=re,1=im): wsA[((g*2+p)*64+L)*8+j]
// ---------------------------------------------------------------------------
__global__ __launch_bounds__(256) void pqg_precompute(
    const float* __restrict__ w, _Float16* __restrict__ wsA)
{
    __shared__ float gm[NLAY * NQ * 8];
    __shared__ float Sr[32 * 32];
    __shared__ float Si[32 * 32];

    const int g = blockIdx.x;
    const int t = threadIdx.x;

    // Gate matrices (Rot = RZ(omega) RY(theta) RZ(phi), verified round 1/2).
    if (t < NLAY * NQ) {
        const float* wp = w + (g * (NLAY * NQ) + t) * 3;
        const float phi = wp[0], theta = wp[1], omega = wp[2];
        const float a = 0.5f * (phi + omega);
        const float bb = 0.5f * (phi - omega);
        const float h = 0.5f * theta;
        const float sa = __sinf(a), ca = __cosf(a);
        const float sb = __sinf(bb), cb = __cosf(bb);
        const float st = __sinf(h), ct = __cosf(h);
        float* m = &gm[t * 8];
        m[0] =  ca * ct;  m[1] = -sa * ct;
        m[2] = -cb * st;  m[3] = -sb * st;
        m[4] =  cb * st;  m[5] = -sb * st;
        m[6] =  ca * ct;  m[7] =  sa * ct;
    }

    // Init S = identity (S[amp][col] = (amp==col)).
#pragma unroll
    for (int r = 0; r < 4; ++r) {
        const int idx = r * 256 + t;
        Sr[idx] = ((idx >> 5) == (idx & 31)) ? 1.0f : 0.0f;
        Si[idx] = 0.0f;
    }
    __syncthreads();

    const int col = t & 31;
    const int p0  = t >> 5;      // 0..7; this thread also does p0+8

    int gate = 0;
#pragma clang loop unroll(disable)
    for (int l = 0; l < NLAY; ++l) {
#pragma clang loop unroll(disable)
        for (int q = 0; q < NQ; ++q, ++gate) {
            const float* m = &gm[gate * 8];
            const float u00r = m[0], u00i = m[1], u01r = m[2], u01i = m[3];
            const float u10r = m[4], u10i = m[5], u11r = m[6], u11i = m[7];
            const int sb = 16 >> q;
            const int lowm = sb - 1;
#pragma unroll
            for (int r = 0; r < 2; ++r) {
                const int p = p0 + r * 8;                       // pair index 0..15
                const int i = ((p & ~lowm) << 1) | (p & lowm);  // insert 0 at bit(sb)
                const int j = i | sb;
                const int ii = i * 32 + col, jj2 = j * 32 + col;
                const float ar = Sr[ii], ai = Si[ii];
                const float br = Sr[jj2], bi = Si[jj2];
                Sr[ii] = u00r * ar - u00i * ai + u01r * br - u01i * bi;
                Si[ii] = u00r * ai + u00i * ar + u01r * bi + u01i * br;
                Sr[jj2] = u10r * ar - u10i * ai + u11r * br - u11i * bi;
                Si[jj2] = u10r * ai + u10i * ar + u11r * bi + u11i * br;
            }
            __syncthreads();
        }

        // CNOT chain (q=0..4, control q, target (q+l+1)%5) as one permutation:
        // S_new[j] = S_old[c0(c1(c2(c3(c4(j)))))], cq(v): if (v&cb) v^=tb.
        const int rr = l + 1;
        float tr[4], ti[4];
#pragma unroll
        for (int r = 0; r < 4; ++r) {
            const int idx = r * 256 + t;
            const int amp = idx >> 5;
            const int cc  = idx & 31;
            int v = amp;
#pragma unroll
            for (int q = 4; q >= 0; --q) {
                const int cb2 = 16 >> q;
                int tq = q + rr; if (tq >= NQ) tq -= NQ;
                const int tb2 = 16 >> tq;
                if (v & cb2) v ^= tb2;
            }
            tr[r] = Sr[v * 32 + cc];
            ti[r] = Si[v * 32 + cc];
        }
        __syncthreads();
#pragma unroll
        for (int r = 0; r < 4; ++r) {
            const int idx = r * 256 + t;
            Sr[idx] = tr[r];
            Si[idx] = ti[r];
        }
        __syncthreads();
    }

    // Emit rows 0..15, both planes: 1024 f16 values, 4 per thread.
#pragma unroll
    for (int r = 0; r < 4; ++r) {
        const int idx = r * 256 + t;        // 0..1023
        const int plane = idx >> 9;
        const int e = idx & 511;
        const int row = e >> 5;             // 0..15
        const int cc  = e & 31;
        const int L = (cc >> 3) * 16 + row;
        const int jj = cc & 7;
        const float val = plane ? Si[row * 32 + cc] : Sr[row * 32 + cc];
        wsA[((g * 2 + plane) * 64 + L) * 8 + jj] = (_Float16)val;
    }
}

// ---------------------------------------------------------------------------
// Kernel B: wave -> one g; each MFMA tile = 16 batches. Identical math to
// round 2 (passed, absmax 3.9e-3). TPB=2, grid 2048 for full CU residency.
// ---------------------------------------------------------------------------
#define TPB 2

__global__ __launch_bounds__(256) void pqg_main(
    const float* __restrict__ x,
    const _Float16* __restrict__ wsA,
    float* __restrict__ out)
{
    const int lane = threadIdx.x & 63;
    const int g = threadIdx.x >> 6;
    const int quad = lane >> 4;
    const int n = lane & 15;

    const half8 Ar = *(const half8*)(wsA + ((g * 2 + 0) * 64 + lane) * 8);
    const half8 Ai = *(const half8*)(wsA + ((g * 2 + 1) * 64 + lane) * 8);

    const int b_block = blockIdx.x * (16 * TPB);

#pragma unroll
    for (int t = 0; t < TPB; ++t) {
        const int b = b_block + t * 16 + n;
        const float* xb = x + b * NQ;

        float c[5], s[5];
#pragma unroll
        for (int q = 0; q < 5; ++q) {
            const float tt = 0.5f * xb[q];
            s[q] = __sinf(tt);
            c[q] = __cosf(tt);
        }

        const float f01 = ((quad & 2) ? s[0] : c[0]) * ((quad & 1) ? s[1] : c[1]);
        const float a0 = f01 * c[2], a1 = f01 * s[2];
        const float b00 = a0 * c[3], b01 = a0 * s[3];
        const float b10 = a1 * c[3], b11 = a1 * s[3];

        half8 Bf;
        Bf[0] = (_Float16)(b00 * c[4]);  Bf[1] = (_Float16)(b00 * s[4]);
        Bf[2] = (_Float16)(b01 * c[4]);  Bf[3] = (_Float16)(b01 * s[4]);
        Bf[4] = (_Float16)(b10 * c[4]);  Bf[5] = (_Float16)(b10 * s[4]);
        Bf[6] = (_Float16)(b11 * c[4]);  Bf[7] = (_Float16)(b11 * s[4]);

        f32x4 accR = {0.f, 0.f, 0.f, 0.f};
        f32x4 accI = {0.f, 0.f, 0.f, 0.f};
        accR = __builtin_amdgcn_mfma_f32_16x16x32_f16(Ar, Bf, accR, 0, 0, 0);
        accI = __builtin_amdgcn_mfma_f32_16x16x32_f16(Ai, Bf, accI, 0, 0, 0);

        // C/D: col = lane&15 (batch n), row = quad*4 + reg (output k).
        float p0 = accR[0] * accR[0] + accI[0] * accI[0];
        float p1 = accR[1] * accR[1] + accI[1] * accI[1];
        float p2 = accR[2] * accR[2] + accI[2] * accI[2];
        float p3 = accR[3] * accR[3] + accI[3] * accI[3];

        float mx = fmaxf(fmaxf(p0, p1), fmaxf(p2, p3));
        mx = fmaxf(mx, __shfl_xor(mx, 16));
        mx = fmaxf(mx, __shfl_xor(mx, 32));
        const float inv = 1.0f / mx;

        float4 o = make_float4(p0 * inv, p1 * inv, p2 * inv, p3 * inv);
        *(float4*)(out + (size_t)b * 64 + g * 16 + quad * 4) = o;
    }
}

extern "C" void kernel_launch(void* const* d_in, const int* in_sizes, int n_in,
                              void* d_out, int out_size, void* d_ws, size_t ws_size,
                              hipStream_t stream) {
    const float* x = (const float*)d_in[0];   // [B, 5]
    const float* w = (const float*)d_in[1];   // [4, 4, 5, 3]
    float* out = (float*)d_out;               // [B, 64]
    _Float16* wsA = (_Float16*)d_ws;          // 8 KB of d_ws

    const int B = in_sizes[0] / NQ;           // 65536

    pqg_precompute<<<NGEN, 256, 0, stream>>>(w, wsA);
    pqg_main<<<B / (16 * TPB), 256, 0, stream>>>(x, wsA, out);
}